// Round 7
// baseline (322.718 us; speedup 1.0000x reference)
//
#include <hip/hip_runtime.h>
#include <hip/hip_bf16.h>

typedef __bf16 bf16_t;
typedef __attribute__((ext_vector_type(8))) __bf16 bf16x8;
typedef __attribute__((ext_vector_type(4))) float f32x4;

#define Bn 8
#define Hh 128
#define Ww 128
#define HW 16384

// ---- ws byte-offset layout ----
#define WP1_B   ((size_t)0)          // 25*4*4*64*8 bf16 = 409600 B
#define WP2_B   ((size_t)409600)     // 9*2*4*64*8 bf16  = 73728 B
#define WPO_B   ((size_t)483328)     // 9*2*4*32*8 bf16  = 36864 B
#define WDCN_B  ((size_t)520192)     // dcn B-frags: 18*4*4*16*8 bf16 = 73728 B  (ends 593920)
#define ZP_B    ((size_t)593920)     // zero page, 256 B (OOB halo source for global_load_lds)
#define BIAS_B  ((size_t)667648)     // 224 f32
#define XT_B    ((size_t)668672)     // Xt NHWC bf16 [8][16384][128] = 33554432 B (LIVE until dcn)
#define F1_B    (XT_B + 33554432)    // feat1 [8][16384][64] bf16; OO f32[8][32][16384] aliases after conv2
#define F2_B    (F1_B + 16777216)    // feat2 [8][16384][64] bf16
// total = 67,777,536 B

// ---- async global->LDS (16B), with compile-safe fallback ----
__device__ __forceinline__ void gload16(const bf16_t* g, bf16_t* l) {
#if __has_builtin(__builtin_amdgcn_global_load_lds)
    __builtin_amdgcn_global_load_lds(
        (const __attribute__((address_space(1))) void*)g,
        (__attribute__((address_space(3))) void*)l, 16, 0, 0);
#else
    *(bf16x8*)l = *(const bf16x8*)g;
#endif
}

// ---------------- prep: swizzle weights into MFMA B-fragment order ----------------
__global__ void prep_kernel(const float* __restrict__ w1, const float* __restrict__ w2,
                            const float* __restrict__ woff, const float* __restrict__ wdcn,
                            const float* __restrict__ b1, const float* __restrict__ b2,
                            const float* __restrict__ boff, const float* __restrict__ bdcn,
                            char* __restrict__ wsb) {
    bf16_t* wp1 = (bf16_t*)(wsb + WP1_B);
    bf16_t* wp2 = (bf16_t*)(wsb + WP2_B);
    bf16_t* wpo = (bf16_t*)(wsb + WPO_B);
    bf16_t* wd  = (bf16_t*)(wsb + WDCN_B);
    float*  bias= (float*)(wsb + BIAS_B);
    float*  zp  = (float*)(wsb + ZP_B);
    int tid = blockIdx.x * blockDim.x + threadIdx.x;
    int nt  = gridDim.x * blockDim.x;
    for (int i = tid; i < 25*4*4*64*8; i += nt) {
        int j = i & 7, q = i >> 3;
        int n = q % 64; q /= 64;
        int g = q & 3;  q >>= 2;
        int ck = q & 3; int t = q >> 2;
        int cin = ck*32 + g*8 + j;
        wp1[i] = (bf16_t)w1[(n*128 + cin)*25 + t];
    }
    for (int i = tid; i < 9*2*4*64*8; i += nt) {
        int j = i & 7, q = i >> 3;
        int n = q % 64; q /= 64;
        int g = q & 3;  q >>= 2;
        int ck = q & 1; int t = q >> 1;
        int cin = ck*32 + g*8 + j;
        wp2[i] = (bf16_t)w2[(n*64 + cin)*9 + t];
    }
    for (int i = tid; i < 9*2*4*32*8; i += nt) {
        int j = i & 7, q = i >> 3;
        int n = q & 31; q >>= 5;
        int g = q & 3;  q >>= 2;
        int ck = q & 1; int t = q >> 1;
        int cin = ck*32 + g*8 + j;
        wpo[i] = (n < 27) ? (bf16_t)woff[(n*64 + cin)*9 + t] : (bf16_t)0.f;
    }
    for (int i = tid; i < 18*4*4*16*8; i += nt) {
        int j = i & 7, f = i >> 3;
        int l15 = f & 15; f >>= 4;
        int l4  = f & 3;  f >>= 2;
        int ntl = f & 3;  int kc = f >> 2;
        int kg = kc*32 + l4*8 + j;
        int tap = kg >> 6, c = kg & 63;
        int n = ntl*16 + l15;
        wd[i] = (bf16_t)wdcn[n*576 + c*9 + tap];
    }
    if (tid < 64) { bias[tid] = b1[tid]; bias[64+tid] = b2[tid]; bias[160+tid] = bdcn[tid]; }
    if (tid >= 64 && tid < 96) { int n = tid - 64; bias[128+n] = (n < 27) ? boff[n] : 0.f; }
    if (tid >= 96 && tid < 160) zp[tid - 96] = 0.f;   // 256 B zero page
}

// ---------------- NCHW f32 (Fi||Fe) -> NHWC bf16 Xt[b][p][128] ----------------
// Fused: also writes the f32 Fi copy into Ff[:, 0:64].
__global__ __launch_bounds__(256) void nhwc_kernel(const float* __restrict__ Fi,
                                                   const float* __restrict__ Fe,
                                                   bf16_t* __restrict__ Xt,
                                                   float* __restrict__ out1) {
    __shared__ bf16_t tile[64][136];
    const int b  = blockIdx.y;
    const int p0 = blockIdx.x * 64;
    const int px = threadIdx.x & 63;
    const int csub = threadIdx.x >> 6;
    for (int ci = 0; ci < 32; ++ci) {
        int c = csub * 32 + ci;
        const float* src = (c < 64) ? (Fi + (((size_t)(b*64 + c)) << 14))
                                    : (Fe + (((size_t)(b*64 + (c-64))) << 14));
        const float v = src[p0 + px];
        tile[px][c] = (bf16_t)v;
        if (c < 64) out1[(((size_t)(b*128 + c)) << 14) + p0 + px] = v;  // Ff Fi-half (f32 NCHW)
    }
    __syncthreads();
    const int px2 = threadIdx.x >> 2;
    const int cc  = (threadIdx.x & 3) * 32;
    bf16x8* dst = (bf16x8*)(Xt + ((size_t)(b*HW) + p0 + px2) * 128 + cc);
    const bf16x8* srcl = (const bf16x8*)(&tile[px2][cc]);
    dst[0] = srcl[0]; dst[1] = srcl[1]; dst[2] = srcl[2]; dst[3] = srcl[3];
}

// ---------------- implicit-GEMM conv, wave tile 64px x 64co ----------------
// Round-7: staging via __builtin_amdgcn_global_load_lds (no VGPR roundtrip, no
// ds_writes) + chgrp-major LDS layout [c:4][pos:576][16B].
//  * Round-6 counters: SQ_LDS_BANK_CONFLICT 3.28M (stride-80B layout, 20i mod 32
//    banks = uneven), VALUBusy 14% staging math, MfmaUtil 32% (=33% of peak).
//  * New layout: reads at (c=l4)*576+pos with l15-consecutive pos -> consecutive
//    16B -> perfectly balanced 8-sweep b128 (minimum) -> ~0 conflicts.
//  * Halo padded to 8 rows x 72 cols: units/ck = 4*576 = 2304 = 9*256 -> 9
//    uniform full-wave staging rounds (no divergence, exec-mask safe).
//  * OOB halo lanes: source = 256B zero page in ws (zero-fill without branches).
//  * Per-thread source pointers precomputed once (ck-invariant + ck*64B step;
//    zp+192B stays inside zero page).
template <int CIN_, int KS, int COUTP, bool LEAKY, bool OUTF32, bool OFFS>
__global__ __launch_bounds__(256) void conv_mfma(const bf16_t* __restrict__ Xt,
                                                 const bf16_t* __restrict__ Wp,
                                                 const float* __restrict__ bias,
                                                 bf16_t* __restrict__ outb,
                                                 float* __restrict__ outf,
                                                 float* __restrict__ out0,
                                                 const bf16_t* __restrict__ zp) {
    constexpr int PAD = KS / 2;
    constexpr int NC  = CIN_ / 32;
    constexpr int NT  = COUTP / 16;        // cout 16-tiles per wave
    __shared__ bf16_t stg[4 * 576 * 8];    // [c][pos(8r x 72c)][8ch] = 36864 B

    const int tid  = threadIdx.x;
    const int lane = tid & 63;
    const int wid  = tid >> 6;             // wave = output row within block
    const int b    = blockIdx.z;
    const int h0   = blockIdx.y * 4;
    const int w0   = blockIdx.x * 64;
    const int l15  = lane & 15;
    const int l4   = lane >> 4;

    f32x4 acc[4][NT];
#pragma unroll
    for (int m = 0; m < 4; ++m)
#pragma unroll
        for (int nt = 0; nt < NT; ++nt)
#pragma unroll
            for (int r = 0; r < 4; ++r) acc[m][nt][r] = 0.f;

    // per-thread staging source pointers (ck=0), OOB -> zero page
    const bf16_t* p[9];
#pragma unroll
    for (int r2 = 0; r2 < 9; ++r2) {
        const int u = r2 * 256 + tid;      // u in [0, 2304)
        const int c = u / 576;
        const int pos = u - c * 576;
        const int srow = pos / 72;
        const int scol = pos - srow * 72;
        const int gh = h0 - PAD + srow, gw = w0 - PAD + scol;
        const bool v = ((unsigned)gh < 128u) && ((unsigned)gw < 128u);
        p[r2] = v ? (Xt + (((size_t)(b * HW) + (gh << 7) + gw)) * CIN_ + c * 8) : zp;
    }

    const bf16x8* wpt = (const bf16x8*)Wp;

    for (int ck = 0; ck < NC; ++ck) {
#pragma unroll
        for (int r2 = 0; r2 < 9; ++r2)
            gload16(p[r2] + ck * 32, &stg[(size_t)(r2 * 256 + tid) * 8]);
        __syncthreads();   // compiler emits vmcnt(0) drain before barrier
        int t = 0;
#pragma unroll
        for (int dy = 0; dy < KS; ++dy) {
#pragma unroll
            for (int dx = 0; dx < KS; ++dx, ++t) {
                bf16x8 a[4];
#pragma unroll
                for (int m = 0; m < 4; ++m)
                    a[m] = *(const bf16x8*)(&stg[(size_t)(l4 * 576 + (wid + dy) * 72 + (m * 16 + l15 + dx)) * 8]);
                bf16x8 bb[NT];
#pragma unroll
                for (int nt = 0; nt < NT; ++nt)
                    bb[nt] = wpt[((size_t)((t * NC + ck) * 4 + l4)) * COUTP + nt * 16 + l15];
#pragma unroll
                for (int m = 0; m < 4; ++m)
#pragma unroll
                    for (int nt = 0; nt < NT; ++nt)
                        acc[m][nt] = __builtin_amdgcn_mfma_f32_16x16x32_bf16(a[m], bb[nt], acc[m][nt], 0, 0, 0);
            }
        }
        __syncthreads();
    }

    // epilogue: C/D 16x16: col(cout) = l15, row(px) = l4*4 + r
    const int hrow = h0 + wid;
#pragma unroll
    for (int m = 0; m < 4; ++m) {
#pragma unroll
        for (int nt = 0; nt < NT; ++nt) {
            const int n = nt * 16 + l15;
            const float bs = bias[n];
#pragma unroll
            for (int r = 0; r < 4; ++r) {
                const int px = w0 + m * 16 + l4 * 4 + r;
                float v = acc[m][nt][r] + bs;
                if (LEAKY) v = (v >= 0.f) ? v : 0.1f * v;
                const size_t pix = (size_t)(hrow << 7) + px;
                if (OUTF32) outf[(((size_t)(b * COUTP + n)) << 14) + pix] = v;         // NCHW f32
                else        outb[(((size_t)(b * HW)) + pix) * COUTP + n] = (bf16_t)v;  // NHWC bf16
                if (OFFS) {
                    if (n < 18) out0[(((size_t)(b * 18 + n)) << 14) + pix] = v;
                }
            }
        }
    }
}

// ---------------- DCNv2 via MFMA, LDS-staged bilinear gathers ----------------
// Round-6 win (dcn ~94 -> <63us): gathers from a 14x14 LDS halo instead of L2
// (the 90us wall was the per-CU L1-miss-queue x L2-latency product). Unchanged.
__global__ __launch_bounds__(256, 4) void dcn_mfma(const bf16_t* __restrict__ Xt,
                                                   const float* __restrict__ OO,
                                                   const bf16_t* __restrict__ Wd,
                                                   const float* __restrict__ bias,
                                                   float* __restrict__ out1) {
    __shared__ bf16_t fe[196 * 64];   // 14x14 pos x 64ch bf16, swizzled = 25088 B

    const int tid  = threadIdx.x;
    const int lane = tid & 63;
    const int wave = tid >> 6;
    const int l15  = lane & 15;
    const int l4   = lane >> 4;
    const int blk  = blockIdx.x;
    const int b    = blk & 7;                  // XCD-pinned batch
    const int tile = blk >> 3;                 // 0..255: 16x16 tiles of 8x8 px
    const int h0   = (tile >> 4) << 3;
    const int w0   = (tile & 15) << 3;
    const int r0   = h0 - 3, c0 = w0 - 3;      // halo origin

    const bf16_t Z0 = (bf16_t)0.f;
    const bf16x8 zv = {Z0, Z0, Z0, Z0, Z0, Z0, Z0, Z0};

    // ---- stage 14x14 Fe halo into LDS (swizzle: slot16B ^= (pos&7)) ----
    for (int i = tid; i < 196 * 8; i += 256) {
        const int pos = i >> 3, slot = i & 7;
        const int rr = pos / 14, cq = pos % 14;
        const int gh = r0 + rr, gw = c0 + cq;
        bf16x8 v = zv;
        if (((unsigned)gh < 128u) && ((unsigned)gw < 128u))
            v = *(const bf16x8*)(Xt + (((size_t)(b * HW) + (gh << 7) + gw)) * 128 + 64 + slot * 8);
        *(bf16x8*)(&fe[pos * 64 + ((slot * 8) ^ ((pos & 7) << 3))]) = v;
    }

    f32x4 acc[4];
#pragma unroll
    for (int nt = 0; nt < 4; ++nt) {
        const float bs = bias[nt * 16 + l15];
        acc[nt][0] = bs; acc[nt][1] = bs; acc[nt][2] = bs; acc[nt][3] = bs;
    }

    // wave's 16 px = 2 rows x 8 cols; px(i): row = h0+2*wave+(i>>3), col = w0+(i&7)
    const int prow = h0 + (wave << 1) + (l15 >> 3);
    const int pcol = w0 + (l15 & 7);
    const size_t oobase = (((size_t)(b * 32)) << 14) + (prow << 7) + pcol;

    // ---- prologue: all 27 OO loads, precompute y/x/m per tap ----
    float ys[9], xs[9], ms[9];
#pragma unroll
    for (int k = 0; k < 9; ++k) {
        const float o1v = OO[oobase + ((size_t)k << 14)];
        const float o2v = OO[oobase + ((size_t)(9 + k) << 14)];
        const float mlv = OO[oobase + ((size_t)(18 + k) << 14)];
        ys[k] = (float)(prow - 1 + (k / 3)) + o1v;
        xs[k] = (float)(pcol - 1 + (k % 3)) + o2v;
        ms[k] = 1.f / (1.f + __expf(-mlv));
    }

    const bf16_t* feb = Xt + ((size_t)(b * HW)) * 128 + 64;   // fallback path
    const bf16x8* Wdv = (const bf16x8*)Wd;

    __syncthreads();

#pragma unroll
    for (int k = 0; k < 9; ++k) {
        const float yk = ys[k], xk = xs[k];
        const float y0f = floorf(yk), x0f = floorf(xk);
        const float fy = yk - y0f, fx = xk - x0f;
        const int y0 = (int)y0f, x0 = (int)x0f;

        const bool vy0 = (unsigned)y0 < 128u;
        const bool vy1 = (unsigned)(y0 + 1) < 128u;
        const bool vx0 = (unsigned)x0 < 128u;
        const bool vx1 = (unsigned)(x0 + 1) < 128u;

        const float mk = ms[k];
        float w00 = (1.f - fy) * (1.f - fx) * mk; w00 = (vy0 && vx0) ? w00 : 0.f;
        float w01 = (1.f - fy) * fx * mk;         w01 = (vy0 && vx1) ? w01 : 0.f;
        float w10 = fy * (1.f - fx) * mk;         w10 = (vy1 && vx0) ? w10 : 0.f;
        float w11 = fy * fx * mk;                 w11 = (vy1 && vx1) ? w11 : 0.f;

        const int ry = y0 - r0, rx = x0 - c0;
        const bool inreg = ((unsigned)ry < 13u) && ((unsigned)rx < 13u);
        const int pos00 = ry * 14 + rx;

#pragma unroll
        for (int cc = 0; cc < 2; ++cc) {
            const int slot = cc * 4 + l4;
            bf16x8 v00, v01, v10, v11;
            if (inreg) {
                const int sw = slot * 8;
                v00 = *(const bf16x8*)(&fe[(pos00     ) * 64 + (sw ^ (((pos00     ) & 7) << 3))]);
                v01 = *(const bf16x8*)(&fe[(pos00 +  1) * 64 + (sw ^ (((pos00 +  1) & 7) << 3))]);
                v10 = *(const bf16x8*)(&fe[(pos00 + 14) * 64 + (sw ^ (((pos00 + 14) & 7) << 3))]);
                v11 = *(const bf16x8*)(&fe[(pos00 + 15) * 64 + (sw ^ (((pos00 + 15) & 7) << 3))]);
            } else {
                const int y0c = min(max(y0, 0), 127), y1c = min(max(y0 + 1, 0), 127);
                const int x0c = min(max(x0, 0), 127), x1c = min(max(x0 + 1, 0), 127);
                const int ch = slot * 8;
                v00 = *(const bf16x8*)(feb + ((size_t)((y0c << 7) + x0c)) * 128 + ch);
                v01 = *(const bf16x8*)(feb + ((size_t)((y0c << 7) + x1c)) * 128 + ch);
                v10 = *(const bf16x8*)(feb + ((size_t)((y1c << 7) + x0c)) * 128 + ch);
                v11 = *(const bf16x8*)(feb + ((size_t)((y1c << 7) + x1c)) * 128 + ch);
            }
            bf16x8 af;
#pragma unroll
            for (int j = 0; j < 8; ++j) {
                af[j] = (bf16_t)(w00 * (float)v00[j] + w01 * (float)v01[j]
                               + w10 * (float)v10[j] + w11 * (float)v11[j]);
            }
            const int s = k * 2 + cc;
#pragma unroll
            for (int nt = 0; nt < 4; ++nt) {
                const bf16x8 bfr = Wdv[((s * 4 + nt) * 4 + l4) * 16 + l15];
                acc[nt] = __builtin_amdgcn_mfma_f32_16x16x32_bf16(af, bfr, acc[nt], 0, 0, 0);
            }
        }
    }

    // epilogue: C row i = l4*4+r -> px(i); col = cout = nt*16+l15
#pragma unroll
    for (int nt = 0; nt < 4; ++nt) {
        const int o = nt * 16 + l15;
#pragma unroll
        for (int r = 0; r < 4; ++r) {
            const int i = l4 * 4 + r;
            const int orow = h0 + (wave << 1) + (i >> 3);
            const int ocol = w0 + (i & 7);
            out1[(((size_t)(b * 128 + 64 + o)) << 14) + (orow << 7) + ocol] = acc[nt][r];
        }
    }
}

extern "C" void kernel_launch(void* const* d_in, const int* in_sizes, int n_in,
                              void* d_out, int out_size, void* d_ws, size_t ws_size,
                              hipStream_t stream) {
    const float* Fi    = (const float*)d_in[0];
    const float* Fe    = (const float*)d_in[1];
    const float* w1    = (const float*)d_in[2];
    const float* b1    = (const float*)d_in[3];
    const float* w2    = (const float*)d_in[4];
    const float* b2    = (const float*)d_in[5];
    const float* w_off = (const float*)d_in[6];
    const float* b_off = (const float*)d_in[7];
    const float* w_dcn = (const float*)d_in[8];
    const float* b_dcn = (const float*)d_in[9];

    char* wsb = (char*)d_ws;
    bf16_t* wp1   = (bf16_t*)(wsb + WP1_B);
    bf16_t* wp2   = (bf16_t*)(wsb + WP2_B);
    bf16_t* wpo   = (bf16_t*)(wsb + WPO_B);
    bf16_t* wdcnf = (bf16_t*)(wsb + WDCN_B);
    float*  bias  = (float*)(wsb + BIAS_B);
    bf16_t* Xt    = (bf16_t*)(wsb + XT_B);
    bf16_t* feat1 = (bf16_t*)(wsb + F1_B);
    bf16_t* feat2 = (bf16_t*)(wsb + F2_B);
    float*  OO    = (float*)(wsb + F1_B);    // NCHW [b][32][HW]; alias: feat1 dead after conv2
    const bf16_t* zp = (const bf16_t*)(wsb + ZP_B);

    float* out0 = (float*)d_out;                   // offset_out [8,18,128,128]
    float* out1 = out0 + (size_t)Bn * 18 * HW;     // Ff [8,128,128,128]

    prep_kernel<<<256, 256, 0, stream>>>(w1, w2, w_off, w_dcn, b1, b2, b_off, b_dcn, wsb);

    nhwc_kernel<<<dim3(256, 8), 256, 0, stream>>>(Fi, Fe, Xt, out1);

    conv_mfma<128, 5, 64, true, false, false>
        <<<dim3(2, 32, 8), 256, 0, stream>>>(Xt, wp1, bias, feat1, nullptr, nullptr, zp);

    conv_mfma<64, 3, 64, true, false, false>
        <<<dim3(2, 32, 8), 256, 0, stream>>>(feat1, wp2, bias + 64, feat2, nullptr, nullptr, zp);

    conv_mfma<64, 3, 32, false, true, true>
        <<<dim3(2, 32, 8), 256, 0, stream>>>(feat2, wpo, bias + 128, nullptr, OO, out0, zp);

    dcn_mfma<<<2048, 256, 0, stream>>>(Xt, OO, wdcnf, bias + 160, out1);
}

// Round 8
// 304.164 us; speedup vs baseline: 1.0610x; 1.0610x over previous
//
#include <hip/hip_runtime.h>
#include <hip/hip_bf16.h>

typedef __bf16 bf16_t;
typedef __attribute__((ext_vector_type(8))) __bf16 bf16x8;
typedef __attribute__((ext_vector_type(4))) float f32x4;

#define Bn 8
#define Hh 128
#define Ww 128
#define HW 16384

// ---- ws byte-offset layout ----
#define WP1_B   ((size_t)0)          // 25*4*4*64*8 bf16 = 409600 B
#define WP2_B   ((size_t)409600)     // 9*2*4*64*8 bf16  = 73728 B
#define WPO_B   ((size_t)483328)     // 9*2*4*32*8 bf16  = 36864 B
#define WDCN_B  ((size_t)520192)     // dcn B-frags: 18*4*4*16*8 bf16 = 73728 B  (ends 593920)
#define ZP_B    ((size_t)593920)     // zero page, 256 B (OOB halo source for global_load_lds)
#define BIAS_B  ((size_t)667648)     // 224 f32
#define XT_B    ((size_t)668672)     // Xt NHWC bf16 [8][16384][128] = 33554432 B (LIVE until dcn)
#define F1_B    (XT_B + 33554432)    // feat1 [8][16384][64] bf16; OO f32[8][32][16384] aliases after conv2
#define F2_B    (F1_B + 16777216)    // feat2 [8][16384][64] bf16
// total = 67,777,536 B

// ---- async global->LDS (16B), with compile-safe fallback ----
__device__ __forceinline__ void gload16(const bf16_t* g, bf16_t* l) {
#if __has_builtin(__builtin_amdgcn_global_load_lds)
    __builtin_amdgcn_global_load_lds(
        (const __attribute__((address_space(1))) void*)g,
        (__attribute__((address_space(3))) void*)l, 16, 0, 0);
#else
    *(bf16x8*)l = *(const bf16x8*)g;
#endif
}

// ---------------- prep: swizzle weights into MFMA B-fragment order ----------------
__global__ void prep_kernel(const float* __restrict__ w1, const float* __restrict__ w2,
                            const float* __restrict__ woff, const float* __restrict__ wdcn,
                            const float* __restrict__ b1, const float* __restrict__ b2,
                            const float* __restrict__ boff, const float* __restrict__ bdcn,
                            char* __restrict__ wsb) {
    bf16_t* wp1 = (bf16_t*)(wsb + WP1_B);
    bf16_t* wp2 = (bf16_t*)(wsb + WP2_B);
    bf16_t* wpo = (bf16_t*)(wsb + WPO_B);
    bf16_t* wd  = (bf16_t*)(wsb + WDCN_B);
    float*  bias= (float*)(wsb + BIAS_B);
    float*  zp  = (float*)(wsb + ZP_B);
    int tid = blockIdx.x * blockDim.x + threadIdx.x;
    int nt  = gridDim.x * blockDim.x;
    for (int i = tid; i < 25*4*4*64*8; i += nt) {
        int j = i & 7, q = i >> 3;
        int n = q % 64; q /= 64;
        int g = q & 3;  q >>= 2;
        int ck = q & 3; int t = q >> 2;
        int cin = ck*32 + g*8 + j;
        wp1[i] = (bf16_t)w1[(n*128 + cin)*25 + t];
    }
    for (int i = tid; i < 9*2*4*64*8; i += nt) {
        int j = i & 7, q = i >> 3;
        int n = q % 64; q /= 64;
        int g = q & 3;  q >>= 2;
        int ck = q & 1; int t = q >> 1;
        int cin = ck*32 + g*8 + j;
        wp2[i] = (bf16_t)w2[(n*64 + cin)*9 + t];
    }
    for (int i = tid; i < 9*2*4*32*8; i += nt) {
        int j = i & 7, q = i >> 3;
        int n = q & 31; q >>= 5;
        int g = q & 3;  q >>= 2;
        int ck = q & 1; int t = q >> 1;
        int cin = ck*32 + g*8 + j;
        wpo[i] = (n < 27) ? (bf16_t)woff[(n*64 + cin)*9 + t] : (bf16_t)0.f;
    }
    for (int i = tid; i < 18*4*4*16*8; i += nt) {
        int j = i & 7, f = i >> 3;
        int l15 = f & 15; f >>= 4;
        int l4  = f & 3;  f >>= 2;
        int ntl = f & 3;  int kc = f >> 2;
        int kg = kc*32 + l4*8 + j;
        int tap = kg >> 6, c = kg & 63;
        int n = ntl*16 + l15;
        wd[i] = (bf16_t)wdcn[n*576 + c*9 + tap];
    }
    if (tid < 64) { bias[tid] = b1[tid]; bias[64+tid] = b2[tid]; bias[160+tid] = bdcn[tid]; }
    if (tid >= 64 && tid < 96) { int n = tid - 64; bias[128+n] = (n < 27) ? boff[n] : 0.f; }
    if (tid >= 96 && tid < 160) zp[tid - 96] = 0.f;   // 256 B zero page
}

// ---------------- NCHW f32 (Fi||Fe) -> NHWC bf16 Xt[b][p][128] ----------------
// Fused: also writes the f32 Fi copy into Ff[:, 0:64].
__global__ __launch_bounds__(256) void nhwc_kernel(const float* __restrict__ Fi,
                                                   const float* __restrict__ Fe,
                                                   bf16_t* __restrict__ Xt,
                                                   float* __restrict__ out1) {
    __shared__ bf16_t tile[64][136];
    const int b  = blockIdx.y;
    const int p0 = blockIdx.x * 64;
    const int px = threadIdx.x & 63;
    const int csub = threadIdx.x >> 6;
    for (int ci = 0; ci < 32; ++ci) {
        int c = csub * 32 + ci;
        const float* src = (c < 64) ? (Fi + (((size_t)(b*64 + c)) << 14))
                                    : (Fe + (((size_t)(b*64 + (c-64))) << 14));
        const float v = src[p0 + px];
        tile[px][c] = (bf16_t)v;
        if (c < 64) out1[(((size_t)(b*128 + c)) << 14) + p0 + px] = v;  // Ff Fi-half (f32 NCHW)
    }
    __syncthreads();
    const int px2 = threadIdx.x >> 2;
    const int cc  = (threadIdx.x & 3) * 32;
    bf16x8* dst = (bf16x8*)(Xt + ((size_t)(b*HW) + p0 + px2) * 128 + cc);
    const bf16x8* srcl = (const bf16x8*)(&tile[px2][cc]);
    dst[0] = srcl[0]; dst[1] = srcl[1]; dst[2] = srcl[2]; dst[3] = srcl[3];
}

// ---------------- implicit-GEMM conv, wave tile 64px x 64co ----------------
// Round-8: pos-major gload_lds staging -- fixes round 7's regression.
//  * Round-7 counters: conflicts 3.28M->0 (good) but FETCH 57->76MB, dur
//    64.5->83.2us: chgrp-major made consecutive lanes read 16B @ 256B stride
//    (1/4 of each 64B segment used; lines evicted before c-group reuse).
//  * Pos-major: unit u = pos*4+q; lanes u..u+3 consume one position's 64B
//    chunk (pos*256B + ck*64B + q*16B) -> full 64B-granule coalescing.
//  * LDS [pos][32ch] (64B/pos, linear dest = stg + u*16B, gload_lds-legal).
//  * ds_read_b128 at 64B stride across l15: start-dword = 16*l15 + 4*l4 mod 32
//    -> 8 (parity,l4) groups tile the 32 banks exactly once, 8 dwords/bank over
//    the minimum 8 clk -> balanced, no excess conflict. (Round-6's stride-40
//    "padding" was what caused its 3.28M conflicts.)
//  * HC padded to 72 -> units 2304 (KS=5) / 1728 (KS=3), both wave-uniform.
//  * OOB/pad lanes source the 256B zero page.
template <int CIN_, int KS, int COUTP, bool LEAKY, bool OUTF32, bool OFFS>
__global__ __launch_bounds__(256) void conv_mfma(const bf16_t* __restrict__ Xt,
                                                 const bf16_t* __restrict__ Wp,
                                                 const float* __restrict__ bias,
                                                 bf16_t* __restrict__ outb,
                                                 float* __restrict__ outf,
                                                 float* __restrict__ out0,
                                                 const bf16_t* __restrict__ zp) {
    constexpr int PAD  = KS / 2;
    constexpr int HR   = 4 + KS - 1;       // 8 (KS=5) / 6 (KS=3)
    constexpr int HC   = 64 + KS - 1;      // 68 / 66 (valid cols)
    constexpr int HCP  = 72;               // padded col count
    constexpr int NPOS = HR * HCP;         // 576 / 432
    constexpr int NU   = NPOS * 4;         // 16B units: 2304 / 1728 (both %64==0)
    constexpr int NR   = (NU + 255) / 256; // staging rounds: 9 / 7 (last partial)
    constexpr int NC   = CIN_ / 32;
    constexpr int NT   = COUTP / 16;       // cout 16-tiles per wave
    __shared__ bf16_t stg[NPOS * 32];      // [pos][32ch] = 36.9 KB / 27.6 KB

    const int tid  = threadIdx.x;
    const int lane = tid & 63;
    const int wid  = tid >> 6;             // wave = output row within block
    const int b    = blockIdx.z;
    const int h0   = blockIdx.y * 4;
    const int w0   = blockIdx.x * 64;
    const int l15  = lane & 15;
    const int l4   = lane >> 4;

    f32x4 acc[4][NT];
#pragma unroll
    for (int m = 0; m < 4; ++m)
#pragma unroll
        for (int nt = 0; nt < NT; ++nt)
#pragma unroll
            for (int r = 0; r < 4; ++r) acc[m][nt][r] = 0.f;

    // per-thread staging source pointers (ck=0), OOB/pad -> zero page
    const bf16_t* p[NR];
#pragma unroll
    for (int r = 0; r < NR; ++r) {
        const int u = r * 256 + tid;
        const int pos = u >> 2, q = u & 3;
        const int srow = pos / HCP;
        const int scol = pos - srow * HCP;
        const int gh = h0 - PAD + srow, gw = w0 - PAD + scol;
        const bool v = (u < NU) && (scol < HC) &&
                       ((unsigned)gh < 128u) && ((unsigned)gw < 128u);
        p[r] = v ? (Xt + (((size_t)(b * HW) + (gh << 7) + gw)) * CIN_ + q * 8)
                 : (zp + q * 8);
    }

    const bf16x8* wpt = (const bf16x8*)Wp;

    for (int ck = 0; ck < NC; ++ck) {
#pragma unroll
        for (int r = 0; r < NR; ++r) {
            const int u = r * 256 + tid;
            if (u < NU) gload16(p[r] + ck * 32, &stg[(size_t)u * 8]);
        }
        __syncthreads();   // compiler emits vmcnt(0) drain before barrier
        int t = 0;
#pragma unroll
        for (int dy = 0; dy < KS; ++dy) {
#pragma unroll
            for (int dx = 0; dx < KS; ++dx, ++t) {
                bf16x8 a[4];
#pragma unroll
                for (int m = 0; m < 4; ++m)
                    a[m] = *(const bf16x8*)(&stg[(size_t)(((wid + dy) * HCP + (m * 16 + l15 + dx)) * 32 + l4 * 8)]);
                bf16x8 bb[NT];
#pragma unroll
                for (int nt = 0; nt < NT; ++nt)
                    bb[nt] = wpt[((size_t)((t * NC + ck) * 4 + l4)) * COUTP + nt * 16 + l15];
#pragma unroll
                for (int m = 0; m < 4; ++m)
#pragma unroll
                    for (int nt = 0; nt < NT; ++nt)
                        acc[m][nt] = __builtin_amdgcn_mfma_f32_16x16x32_bf16(a[m], bb[nt], acc[m][nt], 0, 0, 0);
            }
        }
        __syncthreads();
    }

    // epilogue: C/D 16x16: col(cout) = l15, row(px) = l4*4 + r
    const int hrow = h0 + wid;
#pragma unroll
    for (int m = 0; m < 4; ++m) {
#pragma unroll
        for (int nt = 0; nt < NT; ++nt) {
            const int n = nt * 16 + l15;
            const float bs = bias[n];
#pragma unroll
            for (int r = 0; r < 4; ++r) {
                const int px = w0 + m * 16 + l4 * 4 + r;
                float v = acc[m][nt][r] + bs;
                if (LEAKY) v = (v >= 0.f) ? v : 0.1f * v;
                const size_t pix = (size_t)(hrow << 7) + px;
                if (OUTF32) outf[(((size_t)(b * COUTP + n)) << 14) + pix] = v;         // NCHW f32
                else        outb[(((size_t)(b * HW)) + pix) * COUTP + n] = (bf16_t)v;  // NHWC bf16
                if (OFFS) {
                    if (n < 18) out0[(((size_t)(b * 18 + n)) << 14) + pix] = v;
                }
            }
        }
    }
}

// ---------------- DCNv2 via MFMA, LDS-staged bilinear gathers ----------------
// Round-6 win (dcn ~94 -> <63us): gathers from a 14x14 LDS halo instead of L2
// (the 90us wall was the per-CU L1-miss-queue x L2-latency product). Unchanged.
__global__ __launch_bounds__(256, 4) void dcn_mfma(const bf16_t* __restrict__ Xt,
                                                   const float* __restrict__ OO,
                                                   const bf16_t* __restrict__ Wd,
                                                   const float* __restrict__ bias,
                                                   float* __restrict__ out1) {
    __shared__ bf16_t fe[196 * 64];   // 14x14 pos x 64ch bf16, swizzled = 25088 B

    const int tid  = threadIdx.x;
    const int lane = tid & 63;
    const int wave = tid >> 6;
    const int l15  = lane & 15;
    const int l4   = lane >> 4;
    const int blk  = blockIdx.x;
    const int b    = blk & 7;                  // XCD-pinned batch
    const int tile = blk >> 3;                 // 0..255: 16x16 tiles of 8x8 px
    const int h0   = (tile >> 4) << 3;
    const int w0   = (tile & 15) << 3;
    const int r0   = h0 - 3, c0 = w0 - 3;      // halo origin

    const bf16_t Z0 = (bf16_t)0.f;
    const bf16x8 zv = {Z0, Z0, Z0, Z0, Z0, Z0, Z0, Z0};

    // ---- stage 14x14 Fe halo into LDS (swizzle: slot16B ^= (pos&7)) ----
    for (int i = tid; i < 196 * 8; i += 256) {
        const int pos = i >> 3, slot = i & 7;
        const int rr = pos / 14, cq = pos % 14;
        const int gh = r0 + rr, gw = c0 + cq;
        bf16x8 v = zv;
        if (((unsigned)gh < 128u) && ((unsigned)gw < 128u))
            v = *(const bf16x8*)(Xt + (((size_t)(b * HW) + (gh << 7) + gw)) * 128 + 64 + slot * 8);
        *(bf16x8*)(&fe[pos * 64 + ((slot * 8) ^ ((pos & 7) << 3))]) = v;
    }

    f32x4 acc[4];
#pragma unroll
    for (int nt = 0; nt < 4; ++nt) {
        const float bs = bias[nt * 16 + l15];
        acc[nt][0] = bs; acc[nt][1] = bs; acc[nt][2] = bs; acc[nt][3] = bs;
    }

    // wave's 16 px = 2 rows x 8 cols; px(i): row = h0+2*wave+(i>>3), col = w0+(i&7)
    const int prow = h0 + (wave << 1) + (l15 >> 3);
    const int pcol = w0 + (l15 & 7);
    const size_t oobase = (((size_t)(b * 32)) << 14) + (prow << 7) + pcol;

    // ---- prologue: all 27 OO loads, precompute y/x/m per tap ----
    float ys[9], xs[9], ms[9];
#pragma unroll
    for (int k = 0; k < 9; ++k) {
        const float o1v = OO[oobase + ((size_t)k << 14)];
        const float o2v = OO[oobase + ((size_t)(9 + k) << 14)];
        const float mlv = OO[oobase + ((size_t)(18 + k) << 14)];
        ys[k] = (float)(prow - 1 + (k / 3)) + o1v;
        xs[k] = (float)(pcol - 1 + (k % 3)) + o2v;
        ms[k] = 1.f / (1.f + __expf(-mlv));
    }

    const bf16_t* feb = Xt + ((size_t)(b * HW)) * 128 + 64;   // fallback path
    const bf16x8* Wdv = (const bf16x8*)Wd;

    __syncthreads();

#pragma unroll
    for (int k = 0; k < 9; ++k) {
        const float yk = ys[k], xk = xs[k];
        const float y0f = floorf(yk), x0f = floorf(xk);
        const float fy = yk - y0f, fx = xk - x0f;
        const int y0 = (int)y0f, x0 = (int)x0f;

        const bool vy0 = (unsigned)y0 < 128u;
        const bool vy1 = (unsigned)(y0 + 1) < 128u;
        const bool vx0 = (unsigned)x0 < 128u;
        const bool vx1 = (unsigned)(x0 + 1) < 128u;

        const float mk = ms[k];
        float w00 = (1.f - fy) * (1.f - fx) * mk; w00 = (vy0 && vx0) ? w00 : 0.f;
        float w01 = (1.f - fy) * fx * mk;         w01 = (vy0 && vx1) ? w01 : 0.f;
        float w10 = fy * (1.f - fx) * mk;         w10 = (vy1 && vx0) ? w10 : 0.f;
        float w11 = fy * fx * mk;                 w11 = (vy1 && vx1) ? w11 : 0.f;

        const int ry = y0 - r0, rx = x0 - c0;
        const bool inreg = ((unsigned)ry < 13u) && ((unsigned)rx < 13u);
        const int pos00 = ry * 14 + rx;

#pragma unroll
        for (int cc = 0; cc < 2; ++cc) {
            const int slot = cc * 4 + l4;
            bf16x8 v00, v01, v10, v11;
            if (inreg) {
                const int sw = slot * 8;
                v00 = *(const bf16x8*)(&fe[(pos00     ) * 64 + (sw ^ (((pos00     ) & 7) << 3))]);
                v01 = *(const bf16x8*)(&fe[(pos00 +  1) * 64 + (sw ^ (((pos00 +  1) & 7) << 3))]);
                v10 = *(const bf16x8*)(&fe[(pos00 + 14) * 64 + (sw ^ (((pos00 + 14) & 7) << 3))]);
                v11 = *(const bf16x8*)(&fe[(pos00 + 15) * 64 + (sw ^ (((pos00 + 15) & 7) << 3))]);
            } else {
                const int y0c = min(max(y0, 0), 127), y1c = min(max(y0 + 1, 0), 127);
                const int x0c = min(max(x0, 0), 127), x1c = min(max(x0 + 1, 0), 127);
                const int ch = slot * 8;
                v00 = *(const bf16x8*)(feb + ((size_t)((y0c << 7) + x0c)) * 128 + ch);
                v01 = *(const bf16x8*)(feb + ((size_t)((y0c << 7) + x1c)) * 128 + ch);
                v10 = *(const bf16x8*)(feb + ((size_t)((y1c << 7) + x0c)) * 128 + ch);
                v11 = *(const bf16x8*)(feb + ((size_t)((y1c << 7) + x1c)) * 128 + ch);
            }
            bf16x8 af;
#pragma unroll
            for (int j = 0; j < 8; ++j) {
                af[j] = (bf16_t)(w00 * (float)v00[j] + w01 * (float)v01[j]
                               + w10 * (float)v10[j] + w11 * (float)v11[j]);
            }
            const int s = k * 2 + cc;
#pragma unroll
            for (int nt = 0; nt < 4; ++nt) {
                const bf16x8 bfr = Wdv[((s * 4 + nt) * 4 + l4) * 16 + l15];
                acc[nt] = __builtin_amdgcn_mfma_f32_16x16x32_bf16(af, bfr, acc[nt], 0, 0, 0);
            }
        }
    }

    // epilogue: C row i = l4*4+r -> px(i); col = cout = nt*16+l15
#pragma unroll
    for (int nt = 0; nt < 4; ++nt) {
        const int o = nt * 16 + l15;
#pragma unroll
        for (int r = 0; r < 4; ++r) {
            const int i = l4 * 4 + r;
            const int orow = h0 + (wave << 1) + (i >> 3);
            const int ocol = w0 + (i & 7);
            out1[(((size_t)(b * 128 + 64 + o)) << 14) + (orow << 7) + ocol] = acc[nt][r];
        }
    }
}

extern "C" void kernel_launch(void* const* d_in, const int* in_sizes, int n_in,
                              void* d_out, int out_size, void* d_ws, size_t ws_size,
                              hipStream_t stream) {
    const float* Fi    = (const float*)d_in[0];
    const float* Fe    = (const float*)d_in[1];
    const float* w1    = (const float*)d_in[2];
    const float* b1    = (const float*)d_in[3];
    const float* w2    = (const float*)d_in[4];
    const float* b2    = (const float*)d_in[5];
    const float* w_off = (const float*)d_in[6];
    const float* b_off = (const float*)d_in[7];
    const float* w_dcn = (const float*)d_in[8];
    const float* b_dcn = (const float*)d_in[9];

    char* wsb = (char*)d_ws;
    bf16_t* wp1   = (bf16_t*)(wsb + WP1_B);
    bf16_t* wp2   = (bf16_t*)(wsb + WP2_B);
    bf16_t* wpo   = (bf16_t*)(wsb + WPO_B);
    bf16_t* wdcnf = (bf16_t*)(wsb + WDCN_B);
    float*  bias  = (float*)(wsb + BIAS_B);
    bf16_t* Xt    = (bf16_t*)(wsb + XT_B);
    bf16_t* feat1 = (bf16_t*)(wsb + F1_B);
    bf16_t* feat2 = (bf16_t*)(wsb + F2_B);
    float*  OO    = (float*)(wsb + F1_B);    // NCHW [b][32][HW]; alias: feat1 dead after conv2
    const bf16_t* zp = (const bf16_t*)(wsb + ZP_B);

    float* out0 = (float*)d_out;                   // offset_out [8,18,128,128]
    float* out1 = out0 + (size_t)Bn * 18 * HW;     // Ff [8,128,128,128]

    prep_kernel<<<256, 256, 0, stream>>>(w1, w2, w_off, w_dcn, b1, b2, b_off, b_dcn, wsb);

    nhwc_kernel<<<dim3(256, 8), 256, 0, stream>>>(Fi, Fe, Xt, out1);

    conv_mfma<128, 5, 64, true, false, false>
        <<<dim3(2, 32, 8), 256, 0, stream>>>(Xt, wp1, bias, feat1, nullptr, nullptr, zp);

    conv_mfma<64, 3, 64, true, false, false>
        <<<dim3(2, 32, 8), 256, 0, stream>>>(feat1, wp2, bias + 64, feat2, nullptr, nullptr, zp);

    conv_mfma<64, 3, 32, false, true, true>
        <<<dim3(2, 32, 8), 256, 0, stream>>>(feat2, wpo, bias + 128, nullptr, OO, out0, zp);

    dcn_mfma<<<2048, 256, 0, stream>>>(Xt, OO, wdcnf, bias + 160, out1);
}